// Round 3
// baseline (349.747 us; speedup 1.0000x reference)
//
#include <hip/hip_runtime.h>
#include <math.h>
#include <stdint.h>

#define N_      64
#define M_      2080          // N*(N+1)/2
#define SORTN   4096
#define B_      32
#define TOPK_   5
#define NEIGH_  16
#define NEG_    16
#define TOTAL_  85            // TOPK*(NEIGHBOR+1)
#define KOUT_   101           // NEGATIVE + TOTAL
#define D_      512
#define NT_     1024
#define NWAVE_  (NT_ / 64)    // 16
#define CHUNK_  3             // ceil(2080/1024)
#define VPT_    4             // sort elements per thread (4096/1024)

__device__ __forceinline__ uint64_t shfl_xor_u64(uint64_t x, int mask)
{
    int lo = __shfl_xor((int)(uint32_t)x, mask);
    int hi = __shfl_xor((int)(uint32_t)(x >> 32), mask);
    return ((uint64_t)(uint32_t)hi << 32) | (uint32_t)lo;
}

// in-register compare-exchange between two positions (a = lower global idx)
__device__ __forceinline__ void cas2(uint64_t& a, uint64_t& b, bool up)
{
    bool sw = up ? (a > b) : (a < b);
    uint64_t t = a;
    if (sw) { a = b; b = t; }
}

// Exclusive block scan via wave shfl + LDS combine. 3 barriers.
// After return, s_wsum[NWAVE_-1] holds the block total.
__device__ __forceinline__ int block_scan_excl(int v, int tid, int* s_wsum)
{
    __syncthreads();                       // protect s_wsum reuse
    const int lane = tid & 63;
    const int wave = tid >> 6;
    int x = v;
#pragma unroll
    for (int off = 1; off < 64; off <<= 1) {
        int y = __shfl_up(x, off);
        if (lane >= off) x += y;
    }
    if (lane == 63) s_wsum[wave] = x;
    __syncthreads();
    if (wave == 0) {
        int w = (lane < NWAVE_) ? s_wsum[lane] : 0;
#pragma unroll
        for (int off = 1; off < NWAVE_; off <<= 1) {
            int y = __shfl_up(w, off);
            if (lane >= off) w += y;
        }
        if (lane < NWAVE_) s_wsum[lane] = w;   // inclusive wave totals
    }
    __syncthreads();
    int base = (wave > 0) ? s_wsum[wave - 1] : 0;
    return base + x - v;                   // exclusive prefix
}

// ---------------------------------------------------------------------------
// Kernel 1: per-batch proposal selection. One block (1024 thr) per batch.
// Hybrid bitonic sort: registers (j>=1024) / shfl_xor (j<64) / LDS (64<=j<=512)
// ---------------------------------------------------------------------------
__global__ __launch_bounds__(NT_) void select_kernel(
    const float* __restrict__ score_pred,   // [B,64,64]
    const float* __restrict__ offset_gt,    // [B,64,64,2]
    const float* __restrict__ tmap,         // [B,64,64]
    float* __restrict__ out_pse,            // [B*K,2]
    float* __restrict__ out_off,            // [B*K,2]
    float* __restrict__ out_score)          // [B*K]
{
    __shared__ uint64_t s_kv[SORTN];                 // 32 KB: key<<32 | idx
    __shared__ unsigned char s_r[M_], s_c[M_];
    __shared__ unsigned char sm_s[M_], sm_e[M_];     // sorted moments
    __shared__ unsigned char s_sup[M_], s_sel[M_];
    __shared__ int s_unsupidx[M_];
    __shared__ int s_selidx[TOTAL_];
    __shared__ int s_wsum[NWAVE_];

    const int b   = blockIdx.x;
    const int tid = threadIdx.x;

    // ---- m -> (r,c) triangle table ----
    if (tid < N_) {
        int r  = tid;
        int rs = r * N_ - (r * (r - 1)) / 2;
        for (int k = 0; k < N_ - r; ++k) {
            s_r[rs + k] = (unsigned char)r;
            s_c[rs + k] = (unsigned char)(r + k);
        }
    }
    __syncthreads();

    // ---- load scores, pack sortable uint64 keys into registers ----
    // ascending uint64 sort == descending score, ties ascending original idx
    const float* sp = score_pred + (size_t)b * N_ * N_;
    uint64_t v[VPT_];
#pragma unroll
    for (int k = 0; k < VPT_; ++k) {
        int g = k * NT_ + tid;
        if (g < M_) {
            int r = s_r[g], c = s_c[g];
            uint32_t fb  = __float_as_uint(sp[r * N_ + c]);
            uint32_t ord = (fb & 0x80000000u) ? ~fb : (fb | 0x80000000u);
            uint32_t dk  = ~ord;                        // descending map
            v[k] = ((uint64_t)dk << 32) | (uint32_t)g;
        } else {
            v[k] = ~0ULL;                               // pad: sorts last
        }
    }

    // ---- hybrid bitonic sort (ascending uint64) ----
    for (int kk = 2; kk <= SORTN; kk <<= 1) {
        for (int j = kk >> 1; j > 0; j >>= 1) {
            if (j == 2048) {                 // in-register, kk == 4096
                cas2(v[0], v[2], true);
                cas2(v[1], v[3], true);
            } else if (j == 1024) {          // in-register
                cas2(v[0], v[1], true);
                cas2(v[2], v[3], kk == SORTN);   // kk==2048: upper half desc
            } else if (j >= 64) {            // cross-wave via LDS
                __syncthreads();             // prior reads done before write
#pragma unroll
                for (int k = 0; k < VPT_; ++k)
                    s_kv[k * NT_ + tid] = v[k];
                __syncthreads();
#pragma unroll
                for (int k = 0; k < VPT_; ++k) {
                    int g = k * NT_ + tid;
                    uint64_t o = s_kv[g ^ j];
                    bool up    = ((g & kk) == 0);
                    bool keepS = (((g & j) == 0) == up);
                    v[k] = ((v[k] < o) == keepS) ? v[k] : o;
                }
            } else {                         // intra-wave via shfl_xor
#pragma unroll
                for (int k = 0; k < VPT_; ++k) {
                    int g = k * NT_ + tid;
                    uint64_t o = shfl_xor_u64(v[k], j);
                    bool up    = ((g & kk) == 0);
                    bool keepS = (((tid & j) == 0) == up);
                    v[k] = ((v[k] < o) == keepS) ? v[k] : o;
                }
            }
        }
    }

    // ---- store sorted order to LDS; init state arrays ----
    __syncthreads();
#pragma unroll
    for (int k = 0; k < VPT_; ++k)
        s_kv[k * NT_ + tid] = v[k];
    __syncthreads();
    for (int jj = tid; jj < M_; jj += NT_) {
        int o = (int)(uint32_t)s_kv[jj];
        sm_s[jj] = s_r[o];
        sm_e[jj] = (unsigned char)(s_c[o] + 1);
        s_sup[jj] = 0;
        s_sel[jj] = 0;
        s_unsupidx[jj] = M_ - 1;
    }
    if (tid < TOTAL_) s_selidx[tid] = M_ - 1;
    __syncthreads();

    // ---- NMS while-loop (block-uniform control flow) ----
    const int j0 = tid * CHUNK_;
    int i = 0, cnt = 0;
    while (cnt < TOPK_ && i < M_ - 1) {
        bool freei = (s_sup[i] == 0);
        if (freei) {
            const int si = sm_s[i], ei = sm_e[i];
            unsigned int mkbits = 0;
            int localcnt = 0;
#pragma unroll
            for (int t = 0; t < CHUNK_; ++t) {
                int jj = j0 + t;
                if (jj < M_ && jj > i) {
                    int s = sm_s[jj], e = sm_e[jj];
                    int inter = (e < ei ? e : ei) - (s > si ? s : si);
                    int uni   = (e > ei ? e : ei) - (s < si ? s : si);
                    if (inter > 0 && 2 * inter > uni) {   // iou > 0.5, exact
                        mkbits |= (1u << t);
                        ++localcnt;
                    }
                }
            }
            int run = block_scan_excl(localcnt, tid, s_wsum);
#pragma unroll
            for (int t = 0; t < CHUNK_; ++t) {
                if (mkbits & (1u << t)) {
                    int jj = j0 + t;
                    s_sup[jj] = 1;
                    if (run < NEIGH_) s_sel[jj] = 1;     // cumsum(mask) <= 16
                    ++run;
                }
            }
            if (tid == 0) { s_sup[i] = 1; s_sel[i] = 1; }
            ++cnt;
        }
        ++i;
        __syncthreads();
    }

    // ---- sel compaction ----
    int n_sel, n_unsup;
    {
        int localcnt = 0;
#pragma unroll
        for (int t = 0; t < CHUNK_; ++t) {
            int jj = j0 + t;
            if (jj < M_) localcnt += s_sel[jj];
        }
        int run = block_scan_excl(localcnt, tid, s_wsum);
        n_sel = s_wsum[NWAVE_ - 1];
#pragma unroll
        for (int t = 0; t < CHUNK_; ++t) {
            int jj = j0 + t;
            if (jj < M_ && s_sel[jj]) {
                if (run < TOTAL_) s_selidx[run] = jj;
                ++run;
            }
        }
    }
    // ---- unsup compaction ----
    {
        int localcnt = 0;
#pragma unroll
        for (int t = 0; t < CHUNK_; ++t) {
            int jj = j0 + t;
            if (jj < M_) localcnt += (s_sup[jj] == 0);
        }
        int run = block_scan_excl(localcnt, tid, s_wsum);
        n_unsup = s_wsum[NWAVE_ - 1];
#pragma unroll
        for (int t = 0; t < CHUNK_; ++t) {
            int jj = j0 + t;
            if (jj < M_ && s_sup[jj] == 0) {
                s_unsupidx[run] = jj;
                ++run;
            }
        }
    }
    __syncthreads();

    // ---- final 101 indices + small outputs ----
    if (tid < KOUT_) {
        int idx_sorted;
        if (tid < NEG_) {
            int t = n_unsup - 1 - tid;
            if (t < 0) t = 0;
            idx_sorted = s_unsupidx[t];
        } else {
            int p   = tid - NEG_;
            int pad = TOTAL_ - n_sel;
            idx_sorted = (p < pad) ? s_unsupidx[p] : s_selidx[p - pad];
        }
        int o = (int)(uint32_t)s_kv[idx_sorted];   // original proposal index
        int r = s_r[o], c = s_c[o];
        int gk = b * KOUT_ + tid;
        out_pse[2 * gk + 0] = (float)r;
        out_pse[2 * gk + 1] = (float)(c + 1);
        const float* og = offset_gt + ((size_t)b * N_ * N_ + r * N_ + c) * 2;
        out_off[2 * gk + 0] = og[0];
        out_off[2 * gk + 1] = og[1];
        out_score[gk] = tmap[(size_t)b * N_ * N_ + r * N_ + c];
    }
}

// ---------------------------------------------------------------------------
// Kernel 2: gather prop_feature rows (one block per output row, float4 copy).
// ---------------------------------------------------------------------------
__global__ __launch_bounds__(128) void gather_kernel(
    const float* __restrict__ map2d,        // [B,64,64,512]
    const float* __restrict__ out_pse,      // [B*K,2]
    float* __restrict__ out_feat)           // [B*K,512]
{
    int gk = blockIdx.x;
    int b  = gk / KOUT_;
    int r  = (int)out_pse[2 * gk + 0];
    int c  = (int)out_pse[2 * gk + 1] - 1;
    const float4* src = (const float4*)(map2d + ((size_t)b * N_ * N_ + r * N_ + c) * D_);
    float4*       dst = (float4*)(out_feat + (size_t)gk * D_);
    dst[threadIdx.x] = src[threadIdx.x];
}

extern "C" void kernel_launch(void* const* d_in, const int* in_sizes, int n_in,
                              void* d_out, int out_size, void* d_ws, size_t ws_size,
                              hipStream_t stream)
{
    const float* score_pred = (const float*)d_in[0];
    // d_in[1] = map2d_mask (deterministic triu mask, unused)
    const float* map2d      = (const float*)d_in[2];
    const float* offset_gt  = (const float*)d_in[3];
    const float* tmap       = (const float*)d_in[4];

    float* out       = (float*)d_out;
    float* out_feat  = out;                                   // [3232,512]
    float* out_pse   = out_feat + (size_t)B_ * KOUT_ * D_;    // [3232,2]
    float* out_off   = out_pse  + (size_t)B_ * KOUT_ * 2;     // [3232,2]
    float* out_score = out_off  + (size_t)B_ * KOUT_ * 2;     // [3232]

    select_kernel<<<B_, NT_, 0, stream>>>(score_pred, offset_gt, tmap,
                                          out_pse, out_off, out_score);
    gather_kernel<<<B_ * KOUT_, 128, 0, stream>>>(map2d, out_pse, out_feat);
}